// Round 7
// baseline (1151.986 us; speedup 1.0000x reference)
//
#include <hip/hip_runtime.h>

#define EPSV 1e-10f
#define XS 68   // X row stride in floats: 272B rows, 16B-aligned, 2-way banks max

typedef __attribute__((__ext_vector_type__(8))) short  bhalf8;  // 8 bf16 (4 VGPRs)
typedef __attribute__((__ext_vector_type__(4))) float  f4;
typedef __attribute__((__ext_vector_type__(4))) unsigned u4;

#define MFMA(a,b,c) __builtin_amdgcn_mfma_f32_16x16x32_bf16(a,b,c,0,0,0)

__device__ __forceinline__ bhalf8 ldb16(const unsigned* p) {
    u4 v = *(const u4*)p;
    return __builtin_bit_cast(bhalf8, v);
}

// split 8 consecutive-k fp32 values into hi/lo packed-bf16 fragments
__device__ __forceinline__ void split8(f4 a, f4 b, bhalf8& h, bhalf8& l) {
    float ff[8] = {a[0],a[1],a[2],a[3],b[0],b[1],b[2],b[3]};
    unsigned uh[8]; float fl[8];
#pragma unroll
    for (int i = 0; i < 8; ++i) {
        unsigned bits = __float_as_uint(ff[i]);
        uh[i] = bits & 0xFFFF0000u;
        fl[i] = ff[i] - __uint_as_float(uh[i]);   // exact residual
    }
    u4 hv = { (uh[0]>>16)|uh[1], (uh[2]>>16)|uh[3], (uh[4]>>16)|uh[5], (uh[6]>>16)|uh[7] };
    u4 lv = { (__float_as_uint(fl[0])>>16)|(__float_as_uint(fl[1])&0xFFFF0000u),
              (__float_as_uint(fl[2])>>16)|(__float_as_uint(fl[3])&0xFFFF0000u),
              (__float_as_uint(fl[4])>>16)|(__float_as_uint(fl[5])&0xFFFF0000u),
              (__float_as_uint(fl[6])>>16)|(__float_as_uint(fl[7])&0xFFFF0000u) };
    h = __builtin_bit_cast(bhalf8, hv);
    l = __builtin_bit_cast(bhalf8, lv);
}

// acc[4 ntiles] += A(16x64) * B(64x64); B = frag images (hi, lo), compiler-scheduled
__device__ __forceinline__ void gemm6(f4 acc[4],
                                      bhalf8 ah0, bhalf8 al0, bhalf8 ah1, bhalf8 al1,
                                      const unsigned* Bhi, const unsigned* Blo, int lane) {
#pragma unroll
    for (int t = 0; t < 4; ++t) {
        const unsigned* p0 = Bhi + ((t    ) * 64 + lane) * 4;   // kstep 0 hi
        const unsigned* p1 = Bhi + ((4 + t) * 64 + lane) * 4;   // kstep 1 hi
        const unsigned* q0 = Blo + ((t    ) * 64 + lane) * 4;   // kstep 0 lo
        const unsigned* q1 = Blo + ((4 + t) * 64 + lane) * 4;   // kstep 1 lo
        bhalf8 bl0 = ldb16(q0), bl1 = ldb16(q1);
        bhalf8 bh0 = ldb16(p0), bh1 = ldb16(p1);
        acc[t] = MFMA(ah0, bh0, acc[t]);
        acc[t] = MFMA(ah1, bh1, acc[t]);
        acc[t] = MFMA(al0, bh0, acc[t]);
        acc[t] = MFMA(al1, bh1, acc[t]);
        acc[t] = MFMA(ah0, bl0, acc[t]);
        acc[t] = MFMA(ah1, bl1, acc[t]);
    }
}

// read wave-private A rows from X and split
__device__ __forceinline__ void ldA(const float* Xb, int arow, int lane,
                                    bhalf8& h0, bhalf8& l0, bhalf8& h1, bhalf8& l1) {
    const float* p = Xb + arow * XS + ((lane >> 4) * 8);
    split8(*(const f4*)p,        *(const f4*)(p + 4),  h0, l0);
    split8(*(const f4*)(p + 32), *(const f4*)(p + 36), h1, l1);
}

// ---------- prep: spec2 = species_tab @ gu_w1[64:], rate2 = rating_tab @ gu_w1[64:]
__global__ void prep_tables_k(const float* __restrict__ species_tab,
                              const float* __restrict__ rating_tab,
                              const float* __restrict__ gu_w1,
                              float* __restrict__ spec2, float* __restrict__ rate2) {
    int tid = blockIdx.x * blockDim.x + threadIdx.x;
    if (tid >= 70 * 64) return;
    int row = tid >> 6, e = tid & 63;
    const float* src = (row < 64) ? (species_tab + row * 64) : (rating_tab + (row - 64) * 64);
    float acc = 0.f;
#pragma unroll 8
    for (int k = 0; k < 64; ++k) acc += src[k] * gu_w1[(64 + k) * 64 + e];
    if (row < 64) spec2[row * 64 + e] = acc;
    else          rate2[(row - 64) * 64 + e] = acc;
}

// ---------- prep: qat[b][e] = at_b1[e] + item_tab[iids[b]] . at_w1[64+k][e]
__global__ void prep_qat_k(const float* __restrict__ item_tab, const int* __restrict__ iids,
                           const float* __restrict__ at_w1, const float* __restrict__ at_b1,
                           float* __restrict__ qat, int B) {
    int tid = blockIdx.x * blockDim.x + threadIdx.x;
    if (tid >= B * 64) return;
    int b = tid >> 6, e = tid & 63;
    const float* q = item_tab + (long)iids[b] * 64;
    float acc = at_b1[e];
#pragma unroll 8
    for (int k = 0; k < 64; ++k) acc += q[k] * at_w1[(64 + k) * 64 + e];
    qat[tid] = acc;
}

// ---------- prep: pack 4 weight mats into B-frag hi/lo images (4096 dwords each)
// mats: 0=gu_w2, 1=at_w1[0:64], 2=gu_w1[0:64], 3=gu_w1[64:128]
__global__ void pack_frags_k(const float* __restrict__ gu_w2, const float* __restrict__ at_w1,
                             const float* __restrict__ gu_w1, unsigned* __restrict__ dst) {
    int tid = blockIdx.x * blockDim.x + threadIdx.x;
    if (tid >= 4 * 8 * 64) return;
    int lane = tid & 63, fi = (tid >> 6) & 7, mat = tid >> 9;
    const float* M = (mat == 0) ? gu_w2 : (mat == 1) ? at_w1 : (mat == 2) ? gu_w1 : gu_w1 + 64 * 64;
    int s = fi >> 2, t = fi & 3;
    int n = t * 16 + (lane & 15);
    int kb = s * 32 + (lane >> 4) * 8;
    unsigned hi[4], lo[4];
#pragma unroll
    for (int d = 0; d < 4; ++d) {
        float f0 = M[(kb + 2 * d) * 64 + n], f1 = M[(kb + 2 * d + 1) * 64 + n];
        unsigned b0 = __float_as_uint(f0), b1 = __float_as_uint(f1);
        unsigned h0 = b0 & 0xFFFF0000u, h1 = b1 & 0xFFFF0000u;
        hi[d] = (b0 >> 16) | h1;
        float l0 = f0 - __uint_as_float(h0), l1 = f1 - __uint_as_float(h1);
        lo[d] = (__float_as_uint(l0) >> 16) | (__float_as_uint(l1) & 0xFFFF0000u);
    }
    unsigned* hp = dst + (size_t)mat * 4096 + (size_t)(fi * 64 + lane) * 4;
    unsigned* lp = hp + 2048;
    *(u4*)hp = u4{hi[0], hi[1], hi[2], hi[3]};
    *(u4*)lp = u4{lo[0], lo[1], lo[2], lo[3]};
}

// ---------- main: one block per b; 4 waves; wave owns 16 token rows of X
// __launch_bounds__(256, 2): cap unified VGPR+AGPR at 256/wave -> 2 waves/SIMD.
__global__ __launch_bounds__(256, 2) void item_main_k(
    const float* __restrict__ user_tab, const float* __restrict__ rating_tab,
    const float* __restrict__ ranking_tab,
    const float* __restrict__ gu_b1, const float* __restrict__ gu_b2,
    const float* __restrict__ at_w2, const float* __restrict__ at_b2,
    const float* __restrict__ ag_w, const float* __restrict__ ag_b,
    const float* __restrict__ m_w1, const float* __restrict__ m_b1,
    const float* __restrict__ m_w2, const float* __restrict__ m_b2,
    const float* __restrict__ m_w3, const float* __restrict__ m_b3,
    const int* __restrict__ i_user_pad, const int* __restrict__ i_userk_pad,
    const int* __restrict__ i_user_species_pad,
    const unsigned* __restrict__ frg,   // 4 mats x 4096 dwords (hi @0, lo @+2048)
    const float* __restrict__ spec2, const float* __restrict__ rate2,
    const float* __restrict__ qat,
    float* __restrict__ out, int L)
{
    __shared__ unsigned WL[8192];        // gu_w2 image @0, at_w1a image @4096
    __shared__ float X[64 * XS];
    __shared__ int   uidxb[256], ridb[256], sidb[256], kidb[256];
    __shared__ float maskb[256];
    __shared__ float ZW[4][2][64];
    __shared__ float DW[4][2];
    __shared__ float fin[320];

    const int b    = blockIdx.x;
    const int tid  = threadIdx.x;
    const int lane = tid & 63;
    const int wv   = __builtin_amdgcn_readfirstlane(tid >> 6);

    // stage weight frag images (first 8192 dwords of frg = mats 0,1)
    {
        const u4* src = (const u4*)frg;
        u4* dst = (u4*)WL;
#pragma unroll
        for (int i = 0; i < 8; ++i) dst[tid + i * 256] = src[tid + i * 256];
    }
    // stage per-token indices + mask
    {
        int l = tid;
        int u = 0, rr = 0, ss = 0, kk = 0; float m = 0.f;
        if (l < L) {
            long base = (long)b * L + l;
            u  = i_user_pad[base * 2 + 0];
            rr = i_user_pad[base * 2 + 1];
            ss = i_user_species_pad[base * 2 + 1];
            kk = i_userk_pad[base * 2 + 1];
            m  = (u > 0) ? 1.f : 0.f;
        }
        uidxb[l] = u; ridb[l] = rr; sidb[l] = ss; kidb[l] = kk; maskb[l] = m;
    }
    __syncthreads();

    // per-lane column preloads: col(t) = t*16 + (lane&15)
    float qatv[4], aw2v[4], b1v[4], b2v[4];
#pragma unroll
    for (int t = 0; t < 4; ++t) {
        int col = t * 16 + (lane & 15);
        qatv[t] = qat[b * 64 + col];
        aw2v[t] = at_w2[col];
        b1v[t]  = gu_b1[col];
        b2v[t]  = gu_b2[col];
    }
    const float ab2 = at_b2[0];

    const f4 z4 = {0.f, 0.f, 0.f, 0.f};
    f4 zac0 = z4, zac1 = z4;
    float den0 = 0.f, den1 = 0.f;

    const int arow  = wv * 16 + (lane & 15);         // A-layout row within chunk
    const int drow0 = wv * 16 + (lane >> 4) * 4;     // D-layout first row

    const int nch = (L + 63) >> 6;
    for (int chunk = 0; chunk < nch; ++chunk) {
        const int cbase = chunk * 64;

        int rid4[4], sid4[4], kid4[4]; float mk4[4];
#pragma unroll
        for (int r = 0; r < 4; ++r) {
            int gt = cbase + drow0 + r;
            rid4[r] = ridb[gt]; sid4[r] = sidb[gt]; kid4[r] = kidb[gt]; mk4[r] = maskb[gt];
        }

        bhalf8 ah0, al0, ah1, al1;

        // ---- GEMM1: u1 = p_t @ gu_w1a   (A gathered from user_tab; B = mat2 global)
        {
            const float* pr = user_tab + (size_t)uidxb[cbase + arow] * 64 + ((lane >> 4) * 8);
            split8(*(const f4*)pr,        *(const f4*)(pr + 4),  ah0, al0);
            split8(*(const f4*)(pr + 32), *(const f4*)(pr + 36), ah1, al1);
        }
        f4 u1[4] = {z4, z4, z4, z4};
        gemm6(u1, ah0, al0, ah1, al1, frg + 8192, frg + 8192 + 2048, lane);

        // ---- f1 layer1 -> X (gather spec2 inline) ; GEMM2 vs gu_w2 (LDS hi+lo)
#pragma unroll
        for (int t = 0; t < 4; ++t) {
            int col = t * 16 + (lane & 15);
#pragma unroll
            for (int r = 0; r < 4; ++r) {
                float v = u1[t][r] + spec2[sid4[r] * 64 + col] + b1v[t];
                X[(drow0 + r) * XS + col] = v > 0.f ? v : 0.f;
            }
        }
        ldA(X, arow, lane, ah0, al0, ah1, al1);
        f4 fk[4] = {z4, z4, z4, z4};
        gemm6(fk, ah0, al0, ah1, al1, WL, WL + 2048, lane);
#pragma unroll
        for (int t = 0; t < 4; ++t) {
            int col = t * 16 + (lane & 15);
#pragma unroll
            for (int r = 0; r < 4; ++r)
                fk[t][r] = (fk[t][r] + b2v[t]) * rating_tab[rid4[r] * 64 + col];
        }

        // ---- attn1: GEMM3 vs at_w1a (LDS)
#pragma unroll
        for (int t = 0; t < 4; ++t)
#pragma unroll
            for (int r = 0; r < 4; ++r)
                X[(drow0 + r) * XS + t * 16 + (lane & 15)] = fk[t][r];
        ldA(X, arow, lane, ah0, al0, ah1, al1);
        {
            f4 t1[4] = {z4, z4, z4, z4};
            gemm6(t1, ah0, al0, ah1, al1, WL + 4096, WL + 4096 + 2048, lane);
            float pd[4];
#pragma unroll
            for (int r = 0; r < 4; ++r) {
                float s = 0.f;
#pragma unroll
                for (int t = 0; t < 4; ++t) {
                    float v = t1[t][r] + qatv[t];
                    v = v > 0.f ? v : 0.f;
                    s += v * aw2v[t];
                }
                pd[r] = s;
            }
#pragma unroll
            for (int m = 1; m < 16; m <<= 1)
#pragma unroll
                for (int r = 0; r < 4; ++r) pd[r] += __shfl_xor(pd[r], m, 64);
            float w[4];
#pragma unroll
            for (int r = 0; r < 4; ++r) w[r] = mk4[r] * __expf(pd[r] + ab2);
            float ds = w[0] + w[1] + w[2] + w[3];
            ds += __shfl_xor(ds, 16, 64); ds += __shfl_xor(ds, 32, 64);
            den0 += ds;
#pragma unroll
            for (int t = 0; t < 4; ++t) {
                float s = w[0]*fk[t][0] + w[1]*fk[t][1] + w[2]*fk[t][2] + w[3]*fk[t][3];
                s += __shfl_xor(s, 16, 64); s += __shfl_xor(s, 32, 64);
                zac0[t] += s;
            }
        }

        // ---- f2a layer1 -> X (gather rate2 inline) ; GEMM4 vs gu_w2 (LDS)
#pragma unroll
        for (int t = 0; t < 4; ++t) {
            int col = t * 16 + (lane & 15);
#pragma unroll
            for (int r = 0; r < 4; ++r) {
                float v = u1[t][r] + rate2[rid4[r] * 64 + col] + b1v[t];
                X[(drow0 + r) * XS + col] = v > 0.f ? v : 0.f;
            }
        }
        ldA(X, arow, lane, ah0, al0, ah1, al1);
        f4 f2[4] = {z4, z4, z4, z4};
        gemm6(f2, ah0, al0, ah1, al1, WL, WL + 2048, lane);
#pragma unroll
        for (int t = 0; t < 4; ++t) {
            int col = t * 16 + (lane & 15);
#pragma unroll
            for (int r = 0; r < 4; ++r)
                f2[t][r] = (f2[t][r] + b2v[t]) * ranking_tab[kid4[r] * 64 + col];
        }

        // ---- f2b layer1: GEMM5 vs gu_w1b (global); + u1 + b1, relu
#pragma unroll
        for (int t = 0; t < 4; ++t)
#pragma unroll
            for (int r = 0; r < 4; ++r)
                X[(drow0 + r) * XS + t * 16 + (lane & 15)] = f2[t][r];
        ldA(X, arow, lane, ah0, al0, ah1, al1);
        {
            f4 fb1[4] = {z4, z4, z4, z4};
            gemm6(fb1, ah0, al0, ah1, al1, frg + 12288, frg + 12288 + 2048, lane);
#pragma unroll
            for (int t = 0; t < 4; ++t)
#pragma unroll
                for (int r = 0; r < 4; ++r) {
                    float v = fb1[t][r] + u1[t][r] + b1v[t];
                    X[(drow0 + r) * XS + t * 16 + (lane & 15)] = v > 0.f ? v : 0.f;
                }
        }
        ldA(X, arow, lane, ah0, al0, ah1, al1);
#pragma unroll
        for (int t = 0; t < 4; ++t) f2[t] = z4;
        gemm6(f2, ah0, al0, ah1, al1, WL, WL + 2048, lane);
#pragma unroll
        for (int t = 0; t < 4; ++t)
#pragma unroll
            for (int r = 0; r < 4; ++r)
                f2[t][r] += b2v[t];

        // ---- attn2: GEMM7 vs at_w1a
#pragma unroll
        for (int t = 0; t < 4; ++t)
#pragma unroll
            for (int r = 0; r < 4; ++r)
                X[(drow0 + r) * XS + t * 16 + (lane & 15)] = f2[t][r];
        ldA(X, arow, lane, ah0, al0, ah1, al1);
        {
            f4 t2[4] = {z4, z4, z4, z4};
            gemm6(t2, ah0, al0, ah1, al1, WL + 4096, WL + 4096 + 2048, lane);
            float pd[4];
#pragma unroll
            for (int r = 0; r < 4; ++r) {
                float s = 0.f;
#pragma unroll
                for (int t = 0; t < 4; ++t) {
                    float v = t2[t][r] + qatv[t];
                    v = v > 0.f ? v : 0.f;
                    s += v * aw2v[t];
                }
                pd[r] = s;
            }
#pragma unroll
            for (int m = 1; m < 16; m <<= 1)
#pragma unroll
                for (int r = 0; r < 4; ++r) pd[r] += __shfl_xor(pd[r], m, 64);
            float w[4];
#pragma unroll
            for (int r = 0; r < 4; ++r) w[r] = mk4[r] * __expf(pd[r] + ab2);
            float ds = w[0] + w[1] + w[2] + w[3];
            ds += __shfl_xor(ds, 16, 64); ds += __shfl_xor(ds, 32, 64);
            den1 += ds;
#pragma unroll
            for (int t = 0; t < 4; ++t) {
                float s = w[0]*f2[t][0] + w[1]*f2[t][1] + w[2]*f2[t][2] + w[3]*f2[t][3];
                s += __shfl_xor(s, 16, 64); s += __shfl_xor(s, 32, 64);
                zac1[t] += s;
            }
        }
    } // chunk

    // ---------- cross-wave reduce + head ----------
    if (lane < 16) {
#pragma unroll
        for (int t = 0; t < 4; ++t) {
            ZW[wv][0][t * 16 + lane] = zac0[t];
            ZW[wv][1][t * 16 + lane] = zac1[t];
        }
    }
    if (lane == 0) { DW[wv][0] = den0; DW[wv][1] = den1; }
    __syncthreads();

    float* znorm = fin;        // 128
    float* hcat  = fin + 128;  // 128
    float* hv    = fin + 256;  // 64
    if (tid < 128) {
        int att = tid >> 6, e = tid & 63;
        float z  = ZW[0][att][e] + ZW[1][att][e] + ZW[2][att][e] + ZW[3][att][e];
        float dn = DW[0][att] + DW[1][att] + DW[2][att] + DW[3][att] + EPSV;
        znorm[tid] = z / dn;
    }
    __syncthreads();
    if (tid < 128) {
        int e = tid & 63, half = tid >> 6;
        float a = ag_b[e];
        const float* zn = znorm + half * 64;
#pragma unroll 4
        for (int k = 0; k < 64; ++k) a += zn[k] * ag_w[k * 64 + e];
        hcat[tid] = a > 0.f ? a : 0.f;
    }
    __syncthreads();
    if (tid < 64) {
        float a = m_b1[tid];
#pragma unroll 4
        for (int k = 0; k < 128; ++k) a += hcat[k] * m_w1[k * 64 + tid];
        hv[tid] = a > 0.f ? a : 0.f;
    }
    __syncthreads();
    if (tid < 64) {
        float a = m_b2[tid];
#pragma unroll 4
        for (int k = 0; k < 64; ++k) a += hv[k] * m_w2[k * 64 + tid];
        znorm[tid] = a > 0.f ? a : 0.f;
    }
    __syncthreads();
    if (tid < 64) {
        float a = m_b3[tid];
#pragma unroll 4
        for (int k = 0; k < 64; ++k) a += znorm[k] * m_w3[k * 64 + tid];
        out[(long)b * 64 + tid] = a > 0.f ? a : 0.f;
    }
}

extern "C" void kernel_launch(void* const* d_in, const int* in_sizes, int n_in,
                              void* d_out, int out_size, void* d_ws, size_t ws_size,
                              hipStream_t stream) {
    const float* user_tab    = (const float*)d_in[0];
    const float* item_tab    = (const float*)d_in[1];
    const float* rating_tab  = (const float*)d_in[2];
    const float* ranking_tab = (const float*)d_in[3];
    const float* species_tab = (const float*)d_in[4];
    const float* gu_w1 = (const float*)d_in[5];
    const float* gu_b1 = (const float*)d_in[6];
    const float* gu_w2 = (const float*)d_in[7];
    const float* gu_b2 = (const float*)d_in[8];
    const float* at_w1 = (const float*)d_in[9];
    const float* at_b1 = (const float*)d_in[10];
    const float* at_w2 = (const float*)d_in[11];
    const float* at_b2 = (const float*)d_in[12];
    const float* ag_w  = (const float*)d_in[13];
    const float* ag_b  = (const float*)d_in[14];
    const float* m_w1  = (const float*)d_in[15];
    const float* m_b1  = (const float*)d_in[16];
    const float* m_w2  = (const float*)d_in[17];
    const float* m_b2  = (const float*)d_in[18];
    const float* m_w3  = (const float*)d_in[19];
    const float* m_b3  = (const float*)d_in[20];
    const int* iids               = (const int*)d_in[21];
    const int* i_user_pad         = (const int*)d_in[22];
    const int* i_userk_pad        = (const int*)d_in[23];
    const int* i_user_species_pad = (const int*)d_in[24];

    const int B = in_sizes[21];
    const int L = in_sizes[22] / (B * 2);

    // ws layout (dwords): frag images 4*4096 | spec2 4096 | rate2 384 | qat B*64
    unsigned* frg  = (unsigned*)d_ws;
    float* spec2 = (float*)d_ws + 16384;
    float* rate2 = spec2 + 4096;
    float* qat   = rate2 + 384;

    prep_tables_k<<<(70 * 64 + 255) / 256, 256, 0, stream>>>(species_tab, rating_tab, gu_w1,
                                                             spec2, rate2);
    prep_qat_k<<<(B * 64 + 255) / 256, 256, 0, stream>>>(item_tab, iids, at_w1, at_b1, qat, B);
    pack_frags_k<<<8, 256, 0, stream>>>(gu_w2, at_w1, gu_w1, frg);
    item_main_k<<<B, 256, 0, stream>>>(user_tab, rating_tab, ranking_tab,
                                       gu_b1, gu_b2, at_w2, at_b2, ag_w, ag_b,
                                       m_w1, m_b1, m_w2, m_b2, m_w3, m_b3,
                                       i_user_pad, i_userk_pad, i_user_species_pad,
                                       frg, spec2, rate2, qat, (float*)d_out, L);
}

// Round 8
// 350.013 us; speedup vs baseline: 3.2913x; 3.2913x over previous
//
#include <hip/hip_runtime.h>

#define EPSV 1e-10f
#define XS 68   // LDS row stride in floats: 272B rows, 16B-aligned, 2-way banks max

typedef __attribute__((__ext_vector_type__(8))) short  bhalf8;  // 8 bf16 (4 VGPRs)
typedef __attribute__((__ext_vector_type__(4))) float  f4;
typedef __attribute__((__ext_vector_type__(4))) unsigned u4;

#define MFMA(a,b,c) __builtin_amdgcn_mfma_f32_16x16x32_bf16(a,b,c,0,0,0)

__device__ __forceinline__ bhalf8 ldb16(const unsigned* p) {
    u4 v = *(const u4*)p;
    return __builtin_bit_cast(bhalf8, v);
}

// split 8 consecutive-k fp32 values into hi/lo packed-bf16 fragments
__device__ __forceinline__ void split8(f4 a, f4 b, bhalf8& h, bhalf8& l) {
    float ff[8] = {a[0],a[1],a[2],a[3],b[0],b[1],b[2],b[3]};
    unsigned uh[8]; float fl[8];
#pragma unroll
    for (int i = 0; i < 8; ++i) {
        unsigned bits = __float_as_uint(ff[i]);
        uh[i] = bits & 0xFFFF0000u;
        fl[i] = ff[i] - __uint_as_float(uh[i]);   // exact residual
    }
    u4 hv = { (uh[0]>>16)|uh[1], (uh[2]>>16)|uh[3], (uh[4]>>16)|uh[5], (uh[6]>>16)|uh[7] };
    u4 lv = { (__float_as_uint(fl[0])>>16)|(__float_as_uint(fl[1])&0xFFFF0000u),
              (__float_as_uint(fl[2])>>16)|(__float_as_uint(fl[3])&0xFFFF0000u),
              (__float_as_uint(fl[4])>>16)|(__float_as_uint(fl[5])&0xFFFF0000u),
              (__float_as_uint(fl[6])>>16)|(__float_as_uint(fl[7])&0xFFFF0000u) };
    h = __builtin_bit_cast(bhalf8, hv);
    l = __builtin_bit_cast(bhalf8, lv);
}

// acc[4] += A(16x64)*B(64x64); pipelined one tile ahead, sched_barrier caps
// in-flight B-frags at ~8 (32 VGPRs).
__device__ __forceinline__ void gemm6(f4 acc[4],
                                      bhalf8 ah0, bhalf8 al0, bhalf8 ah1, bhalf8 al1,
                                      const unsigned* Bhi, const unsigned* Blo, int lane) {
    bhalf8 bh0 = ldb16(Bhi + (0 * 64 + lane) * 4);
    bhalf8 bh1 = ldb16(Bhi + (4 * 64 + lane) * 4);
    bhalf8 bl0 = ldb16(Blo + (0 * 64 + lane) * 4);
    bhalf8 bl1 = ldb16(Blo + (4 * 64 + lane) * 4);
#pragma unroll
    for (int t = 0; t < 4; ++t) {
        bhalf8 nh0, nh1, nl0, nl1;
        if (t < 3) {
            nh0 = ldb16(Bhi + ((t + 1) * 64 + lane) * 4);
            nh1 = ldb16(Bhi + ((t + 5) * 64 + lane) * 4);
            nl0 = ldb16(Blo + ((t + 1) * 64 + lane) * 4);
            nl1 = ldb16(Blo + ((t + 5) * 64 + lane) * 4);
        }
        acc[t] = MFMA(ah0, bh0, acc[t]);
        acc[t] = MFMA(ah1, bh1, acc[t]);
        acc[t] = MFMA(al0, bh0, acc[t]);
        acc[t] = MFMA(al1, bh1, acc[t]);
        acc[t] = MFMA(ah0, bl0, acc[t]);
        acc[t] = MFMA(ah1, bl1, acc[t]);
        __builtin_amdgcn_sched_barrier(0);
        if (t < 3) { bh0 = nh0; bh1 = nh1; bl0 = nl0; bl1 = nl1; }
    }
}

// read wave-private A rows from X and split
__device__ __forceinline__ void ldA(const float* Xb, int arow, int lane,
                                    bhalf8& h0, bhalf8& l0, bhalf8& h1, bhalf8& l1) {
    const float* p = Xb + arow * XS + ((lane >> 4) * 8);
    split8(*(const f4*)p,        *(const f4*)(p + 4),  h0, l0);
    split8(*(const f4*)(p + 32), *(const f4*)(p + 36), h1, l1);
}

// ---------- prep: spec2 = species_tab @ gu_w1[64:], rate2 = rating_tab @ gu_w1[64:]
__global__ void prep_tables_k(const float* __restrict__ species_tab,
                              const float* __restrict__ rating_tab,
                              const float* __restrict__ gu_w1,
                              float* __restrict__ spec2, float* __restrict__ rate2) {
    int tid = blockIdx.x * blockDim.x + threadIdx.x;
    if (tid >= 70 * 64) return;
    int row = tid >> 6, e = tid & 63;
    const float* src = (row < 64) ? (species_tab + row * 64) : (rating_tab + (row - 64) * 64);
    float acc = 0.f;
#pragma unroll 8
    for (int k = 0; k < 64; ++k) acc += src[k] * gu_w1[(64 + k) * 64 + e];
    if (row < 64) spec2[row * 64 + e] = acc;
    else          rate2[(row - 64) * 64 + e] = acc;
}

// ---------- prep: qat[b][e] = at_b1[e] + item_tab[iids[b]] . at_w1[64+k][e]
__global__ void prep_qat_k(const float* __restrict__ item_tab, const int* __restrict__ iids,
                           const float* __restrict__ at_w1, const float* __restrict__ at_b1,
                           float* __restrict__ qat, int B) {
    int tid = blockIdx.x * blockDim.x + threadIdx.x;
    if (tid >= B * 64) return;
    int b = tid >> 6, e = tid & 63;
    const float* q = item_tab + (long)iids[b] * 64;
    float acc = at_b1[e];
#pragma unroll 8
    for (int k = 0; k < 64; ++k) acc += q[k] * at_w1[(64 + k) * 64 + e];
    qat[tid] = acc;
}

// ---------- prep: pack 4 weight mats into B-frag hi/lo images (4096 dwords each)
// mats: 0=gu_w2, 1=at_w1[0:64], 2=gu_w1[0:64], 3=gu_w1[64:128]
__global__ void pack_frags_k(const float* __restrict__ gu_w2, const float* __restrict__ at_w1,
                             const float* __restrict__ gu_w1, unsigned* __restrict__ dst) {
    int tid = blockIdx.x * blockDim.x + threadIdx.x;
    if (tid >= 4 * 8 * 64) return;
    int lane = tid & 63, fi = (tid >> 6) & 7, mat = tid >> 9;
    const float* M = (mat == 0) ? gu_w2 : (mat == 1) ? at_w1 : (mat == 2) ? gu_w1 : gu_w1 + 64 * 64;
    int s = fi >> 2, t = fi & 3;
    int n = t * 16 + (lane & 15);
    int kb = s * 32 + (lane >> 4) * 8;
    unsigned hi[4], lo[4];
#pragma unroll
    for (int d = 0; d < 4; ++d) {
        float f0 = M[(kb + 2 * d) * 64 + n], f1 = M[(kb + 2 * d + 1) * 64 + n];
        unsigned b0 = __float_as_uint(f0), b1 = __float_as_uint(f1);
        unsigned h0 = b0 & 0xFFFF0000u, h1 = b1 & 0xFFFF0000u;
        hi[d] = (b0 >> 16) | h1;
        float l0 = f0 - __uint_as_float(h0), l1 = f1 - __uint_as_float(h1);
        lo[d] = (__float_as_uint(l0) >> 16) | (__float_as_uint(l1) & 0xFFFF0000u);
    }
    unsigned* hp = dst + (size_t)mat * 4096 + (size_t)(fi * 64 + lane) * 4;
    unsigned* lp = hp + 2048;
    *(u4*)hp = u4{hi[0], hi[1], hi[2], hi[3]};
    *(u4*)lp = u4{lo[0], lo[1], lo[2], lo[3]};
}

// ---------- main: one block per b; 4 waves; wave owns 16 token rows of X/U
// cap unified VGPR+AGPR at 256/wave -> 2 waves/SIMD; demand lowered via LDS offload.
__global__ __launch_bounds__(256, 2) void item_main_k(
    const float* __restrict__ user_tab, const float* __restrict__ rating_tab,
    const float* __restrict__ ranking_tab,
    const float* __restrict__ gu_b1, const float* __restrict__ gu_b2,
    const float* __restrict__ at_w2, const float* __restrict__ at_b2,
    const float* __restrict__ ag_w, const float* __restrict__ ag_b,
    const float* __restrict__ m_w1, const float* __restrict__ m_b1,
    const float* __restrict__ m_w2, const float* __restrict__ m_b2,
    const float* __restrict__ m_w3, const float* __restrict__ m_b3,
    const int* __restrict__ i_user_pad, const int* __restrict__ i_userk_pad,
    const int* __restrict__ i_user_species_pad,
    const unsigned* __restrict__ frg,   // 4 mats x 4096 dwords (hi @0, lo @+2048)
    const float* __restrict__ spec2, const float* __restrict__ rate2,
    const float* __restrict__ qat,
    float* __restrict__ out, int L)
{
    __shared__ unsigned WL[8192];        // gu_w2 image @0, at_w1a image @4096
    __shared__ float X[64 * XS];         // activation ping buffer (wave-private rows)
    __shared__ float U[64 * XS];         // u1' = p_t @ gu_w1a + gu_b1 (held per chunk)
    __shared__ int   uidxb[256], ridb[256], sidb[256], kidb[256];
    __shared__ float ZW[4][2][64];
    __shared__ float DW[4][2];
    __shared__ float fin[320];

    const int b    = blockIdx.x;
    const int tid  = threadIdx.x;
    const int lane = tid & 63;
    const int wv   = __builtin_amdgcn_readfirstlane(tid >> 6);

    // stage weight frag images (first 8192 dwords of frg = mats 0,1)
    {
        const u4* src = (const u4*)frg;
        u4* dst = (u4*)WL;
#pragma unroll
        for (int i = 0; i < 8; ++i) dst[tid + i * 256] = src[tid + i * 256];
    }
    // stage per-token indices
    {
        int l = tid;
        int u = 0, rr = 0, ss = 0, kk = 0;
        if (l < L) {
            long base = (long)b * L + l;
            u  = i_user_pad[base * 2 + 0];
            rr = i_user_pad[base * 2 + 1];
            ss = i_user_species_pad[base * 2 + 1];
            kk = i_userk_pad[base * 2 + 1];
        }
        uidxb[l] = u; ridb[l] = rr; sidb[l] = ss; kidb[l] = kk;
    }
    __syncthreads();

    // per-lane column preloads: col(t) = t*16 + (lane&15)
    float qatv[4], aw2v[4], b1v[4], b2v[4];
#pragma unroll
    for (int t = 0; t < 4; ++t) {
        int col = t * 16 + (lane & 15);
        qatv[t] = qat[b * 64 + col];
        aw2v[t] = at_w2[col];
        b1v[t]  = gu_b1[col];
        b2v[t]  = gu_b2[col];
    }
    const float ab2 = at_b2[0];

    const f4 z4 = {0.f, 0.f, 0.f, 0.f};
    f4 zac0 = z4, zac1 = z4;
    float den0 = 0.f, den1 = 0.f;

    const int arow  = wv * 16 + (lane & 15);         // A-layout row within chunk
    const int drow0 = wv * 16 + (lane >> 4) * 4;     // D-layout first row
    const int lcol  = lane & 15;

    const int nch = (L + 63) >> 6;
    for (int chunk = 0; chunk < nch; ++chunk) {
        const int cbase = chunk * 64;

        int rid4[4], sid4[4], kid4[4];
#pragma unroll
        for (int r = 0; r < 4; ++r) {
            int gt = cbase + drow0 + r;
            rid4[r] = ridb[gt]; sid4[r] = sidb[gt]; kid4[r] = kidb[gt];
        }

        bhalf8 ah0, al0, ah1, al1;

        // ---- GEMM1: u1 = p_t @ gu_w1a (A gathered from user_tab; B = mat2 global/L2)
        {
            const float* pr = user_tab + (size_t)uidxb[cbase + arow] * 64 + ((lane >> 4) * 8);
            split8(*(const f4*)pr,        *(const f4*)(pr + 4),  ah0, al0);
            split8(*(const f4*)(pr + 32), *(const f4*)(pr + 36), ah1, al1);
        }
        {
            f4 u1[4] = {z4, z4, z4, z4};
            gemm6(u1, ah0, al0, ah1, al1, frg + 8192, frg + 8192 + 2048, lane);
            // u1' = u1 + gu_b1 -> U (reused by f1/f2a/f2b); also f1 layer1 -> X
#pragma unroll
            for (int t = 0; t < 4; ++t) {
                int col = t * 16 + lcol;
#pragma unroll
                for (int r = 0; r < 4; ++r) {
                    float up = u1[t][r] + b1v[t];
                    U[(drow0 + r) * XS + col] = up;
                    float v = up + spec2[sid4[r] * 64 + col];
                    X[(drow0 + r) * XS + col] = v > 0.f ? v : 0.f;
                }
            }
        }

        // ---- GEMM2 vs gu_w2 (LDS): fk = relu1 @ gu_w2; (fk+b2)*er -> X
        ldA(X, arow, lane, ah0, al0, ah1, al1);
        {
            f4 fk[4] = {z4, z4, z4, z4};
            gemm6(fk, ah0, al0, ah1, al1, WL, WL + 2048, lane);
#pragma unroll
            for (int t = 0; t < 4; ++t) {
                int col = t * 16 + lcol;
#pragma unroll
                for (int r = 0; r < 4; ++r)
                    X[(drow0 + r) * XS + col] =
                        (fk[t][r] + b2v[t]) * rating_tab[rid4[r] * 64 + col];
            }
        }

        // ---- attn1: GEMM3 vs at_w1a (LDS); f1 values reloaded from X for z-accum
        ldA(X, arow, lane, ah0, al0, ah1, al1);
        {
            f4 t1[4] = {z4, z4, z4, z4};
            gemm6(t1, ah0, al0, ah1, al1, WL + 4096, WL + 4096 + 2048, lane);
            float pd[4];
#pragma unroll
            for (int r = 0; r < 4; ++r) {
                float s = 0.f;
#pragma unroll
                for (int t = 0; t < 4; ++t) {
                    float v = t1[t][r] + qatv[t];
                    v = v > 0.f ? v : 0.f;
                    s += v * aw2v[t];
                }
                pd[r] = s;
            }
#pragma unroll
            for (int m = 1; m < 16; m <<= 1)
#pragma unroll
                for (int r = 0; r < 4; ++r) pd[r] += __shfl_xor(pd[r], m, 64);
            float w[4];
#pragma unroll
            for (int r = 0; r < 4; ++r)
                w[r] = (uidxb[cbase + drow0 + r] > 0) ? __expf(pd[r] + ab2) : 0.f;
            float ds = w[0] + w[1] + w[2] + w[3];
            ds += __shfl_xor(ds, 16, 64); ds += __shfl_xor(ds, 32, 64);
            den0 += ds;
#pragma unroll
            for (int t = 0; t < 4; ++t) {
                int col = t * 16 + lcol;
                float s = w[0] * X[(drow0 + 0) * XS + col] + w[1] * X[(drow0 + 1) * XS + col]
                        + w[2] * X[(drow0 + 2) * XS + col] + w[3] * X[(drow0 + 3) * XS + col];
                s += __shfl_xor(s, 16, 64); s += __shfl_xor(s, 32, 64);
                zac0[t] += s;
            }
        }

        // ---- f2a layer1 -> X (u1' from U + rate2 gather) ; GEMM4 vs gu_w2 (LDS)
#pragma unroll
        for (int t = 0; t < 4; ++t) {
            int col = t * 16 + lcol;
#pragma unroll
            for (int r = 0; r < 4; ++r) {
                float v = U[(drow0 + r) * XS + col] + rate2[rid4[r] * 64 + col];
                X[(drow0 + r) * XS + col] = v > 0.f ? v : 0.f;
            }
        }
        ldA(X, arow, lane, ah0, al0, ah1, al1);
        {
            f4 f2[4] = {z4, z4, z4, z4};
            gemm6(f2, ah0, al0, ah1, al1, WL, WL + 2048, lane);
#pragma unroll
            for (int t = 0; t < 4; ++t) {
                int col = t * 16 + lcol;
#pragma unroll
                for (int r = 0; r < 4; ++r)
                    X[(drow0 + r) * XS + col] =
                        (f2[t][r] + b2v[t]) * ranking_tab[kid4[r] * 64 + col];
            }
        }

        // ---- f2b layer1: GEMM5 vs gu_w1b (global/L2); + u1' from U, relu -> X
        ldA(X, arow, lane, ah0, al0, ah1, al1);
        {
            f4 fb1[4] = {z4, z4, z4, z4};
            gemm6(fb1, ah0, al0, ah1, al1, frg + 12288, frg + 12288 + 2048, lane);
#pragma unroll
            for (int t = 0; t < 4; ++t) {
                int col = t * 16 + lcol;
#pragma unroll
                for (int r = 0; r < 4; ++r) {
                    float v = fb1[t][r] + U[(drow0 + r) * XS + col];
                    X[(drow0 + r) * XS + col] = v > 0.f ? v : 0.f;
                }
            }
        }
        // ---- f2b = relu @ gu_w2 + b2 -> X ; GEMM6 vs gu_w2 (LDS)
        ldA(X, arow, lane, ah0, al0, ah1, al1);
        {
            f4 f2[4] = {z4, z4, z4, z4};
            gemm6(f2, ah0, al0, ah1, al1, WL, WL + 2048, lane);
#pragma unroll
            for (int t = 0; t < 4; ++t) {
                int col = t * 16 + lcol;
#pragma unroll
                for (int r = 0; r < 4; ++r)
                    X[(drow0 + r) * XS + col] = f2[t][r] + b2v[t];
            }
        }

        // ---- attn2: GEMM7 vs at_w1a; f2b reloaded from X for z-accum
        ldA(X, arow, lane, ah0, al0, ah1, al1);
        {
            f4 t2[4] = {z4, z4, z4, z4};
            gemm6(t2, ah0, al0, ah1, al1, WL + 4096, WL + 4096 + 2048, lane);
            float pd[4];
#pragma unroll
            for (int r = 0; r < 4; ++r) {
                float s = 0.f;
#pragma unroll
                for (int t = 0; t < 4; ++t) {
                    float v = t2[t][r] + qatv[t];
                    v = v > 0.f ? v : 0.f;
                    s += v * aw2v[t];
                }
                pd[r] = s;
            }
#pragma unroll
            for (int m = 1; m < 16; m <<= 1)
#pragma unroll
                for (int r = 0; r < 4; ++r) pd[r] += __shfl_xor(pd[r], m, 64);
            float w[4];
#pragma unroll
            for (int r = 0; r < 4; ++r)
                w[r] = (uidxb[cbase + drow0 + r] > 0) ? __expf(pd[r] + ab2) : 0.f;
            float ds = w[0] + w[1] + w[2] + w[3];
            ds += __shfl_xor(ds, 16, 64); ds += __shfl_xor(ds, 32, 64);
            den1 += ds;
#pragma unroll
            for (int t = 0; t < 4; ++t) {
                int col = t * 16 + lcol;
                float s = w[0] * X[(drow0 + 0) * XS + col] + w[1] * X[(drow0 + 1) * XS + col]
                        + w[2] * X[(drow0 + 2) * XS + col] + w[3] * X[(drow0 + 3) * XS + col];
                s += __shfl_xor(s, 16, 64); s += __shfl_xor(s, 32, 64);
                zac1[t] += s;
            }
        }
    } // chunk

    // ---------- cross-wave reduce + head ----------
    if (lane < 16) {
#pragma unroll
        for (int t = 0; t < 4; ++t) {
            ZW[wv][0][t * 16 + lane] = zac0[t];
            ZW[wv][1][t * 16 + lane] = zac1[t];
        }
    }
    if (lane == 0) { DW[wv][0] = den0; DW[wv][1] = den1; }
    __syncthreads();

    float* znorm = fin;        // 128
    float* hcat  = fin + 128;  // 128
    float* hv    = fin + 256;  // 64
    if (tid < 128) {
        int att = tid >> 6, e = tid & 63;
        float z  = ZW[0][att][e] + ZW[1][att][e] + ZW[2][att][e] + ZW[3][att][e];
        float dn = DW[0][att] + DW[1][att] + DW[2][att] + DW[3][att] + EPSV;
        znorm[tid] = z / dn;
    }
    __syncthreads();
    if (tid < 128) {
        int e = tid & 63, half = tid >> 6;
        float a = ag_b[e];
        const float* zn = znorm + half * 64;
#pragma unroll 4
        for (int k = 0; k < 64; ++k) a += zn[k] * ag_w[k * 64 + e];
        hcat[tid] = a > 0.f ? a : 0.f;
    }
    __syncthreads();
    if (tid < 64) {
        float a = m_b1[tid];
#pragma unroll 4
        for (int k = 0; k < 128; ++k) a += hcat[k] * m_w1[k * 64 + tid];
        hv[tid] = a > 0.f ? a : 0.f;
    }
    __syncthreads();
    if (tid < 64) {
        float a = m_b2[tid];
#pragma unroll 4
        for (int k = 0; k < 64; ++k) a += hv[k] * m_w2[k * 64 + tid];
        znorm[tid] = a > 0.f ? a : 0.f;
    }
    __syncthreads();
    if (tid < 64) {
        float a = m_b3[tid];
#pragma unroll 4
        for (int k = 0; k < 64; ++k) a += znorm[k] * m_w3[k * 64 + tid];
        out[(long)b * 64 + tid] = a > 0.f ? a : 0.f;
    }
}

extern "C" void kernel_launch(void* const* d_in, const int* in_sizes, int n_in,
                              void* d_out, int out_size, void* d_ws, size_t ws_size,
                              hipStream_t stream) {
    const float* user_tab    = (const float*)d_in[0];
    const float* item_tab    = (const float*)d_in[1];
    const float* rating_tab  = (const float*)d_in[2];
    const float* ranking_tab = (const float*)d_in[3];
    const float* species_tab = (const float*)d_in[4];
    const float* gu_w1 = (const float*)d_in[5];
    const float* gu_b1 = (const float*)d_in[6];
    const float* gu_w2 = (const float*)d_in[7];
    const float* gu_b2 = (const float*)d_in[8];
    const float* at_w1 = (const float*)d_in[9];
    const float* at_b1 = (const float*)d_in[10];
    const float* at_w2 = (const float*)d_in[11];
    const float* at_b2 = (const float*)d_in[12];
    const float* ag_w  = (const float*)d_in[13];
    const float* ag_b  = (const float*)d_in[14];
    const float* m_w1  = (const float*)d_in[15];
    const float* m_b1  = (const float*)d_in[16];
    const float* m_w2  = (const float*)d_in[17];
    const float* m_b2  = (const float*)d_in[18];
    const float* m_w3  = (const float*)d_in[19];
    const float* m_b3  = (const float*)d_in[20];
    const int* iids               = (const int*)d_in[21];
    const int* i_user_pad         = (const int*)d_in[22];
    const int* i_userk_pad        = (const int*)d_in[23];
    const int* i_user_species_pad = (const int*)d_in[24];

    const int B = in_sizes[21];
    const int L = in_sizes[22] / (B * 2);

    // ws layout (dwords): frag images 4*4096 | spec2 4096 | rate2 384 | qat B*64
    unsigned* frg  = (unsigned*)d_ws;
    float* spec2 = (float*)d_ws + 16384;
    float* rate2 = spec2 + 4096;
    float* qat   = rate2 + 384;

    prep_tables_k<<<(70 * 64 + 255) / 256, 256, 0, stream>>>(species_tab, rating_tab, gu_w1,
                                                             spec2, rate2);
    prep_qat_k<<<(B * 64 + 255) / 256, 256, 0, stream>>>(item_tab, iids, at_w1, at_b1, qat, B);
    pack_frags_k<<<8, 256, 0, stream>>>(gu_w2, at_w1, gu_w1, frg);
    item_main_k<<<B, 256, 0, stream>>>(user_tab, rating_tab, ranking_tab,
                                       gu_b1, gu_b2, at_w2, at_b2, ag_w, ag_b,
                                       m_w1, m_b1, m_w2, m_b2, m_w3, m_b3,
                                       i_user_pad, i_userk_pad, i_user_species_pad,
                                       frg, spec2, rate2, qat, (float*)d_out, L);
}